// Round 9
// baseline (387.479 us; speedup 1.0000x reference)
//
#include <hip/hip_runtime.h>
#include <cstddef>

#define B_   64
#define N_   512
#define NV_  32768
#define NE_  8192
#define NNZ_ 262144
#define SNNZ_ 24576
#define D_   300
#define HID_ 256
#define NC_  10
#define VOCAB_ 30000

#define SCAN_TOT (NE_ + NV_ + NE_)      // 49152 counts, contiguous [cnt_e|cnt_v|cnt_s]
#define SCAN_NCH (SCAN_TOT / 1024)      // 48 chunks
#define SEG1_CH  (NE_ / 1024)           // 8  (start of cnt_v chunks)
#define SEG2_CH  ((NE_ + NV_) / 1024)   // 40 (start of cnt_s chunks)

using u16 = unsigned short;
typedef __attribute__((ext_vector_type(8))) short short8;
typedef __attribute__((ext_vector_type(4))) float f32x4;

__device__ __forceinline__ float bf2f(u16 v) {
    union { unsigned int u; float f; } uf;
    uf.u = ((unsigned int)v) << 16;
    return uf.f;
}
__device__ __forceinline__ u16 f2bf(float f) {
    union { float f; unsigned int u; } uf; uf.f = f;
    unsigned int u = uf.u;
    unsigned int r = u + 0x7fffu + ((u >> 16) & 1u);
    return (u16)(r >> 16);
}

// ---------------- CSR build ----------------------------------------------------------
// fused histogram: e-counts from inc_cols, v-counts from inc_rows, s-counts from sent_cols
__global__ __launch_bounds__(256) void hist_kernel(const int* __restrict__ inc_rows,
                                                   const int* __restrict__ inc_cols,
                                                   const int* __restrict__ sent_cols,
                                                   int* __restrict__ cnt) {
    int i = blockIdx.x * 256 + threadIdx.x;
    atomicAdd(&cnt[inc_cols[i]], 1);
    atomicAdd(&cnt[NE_ + inc_rows[i]], 1);
    if (i < SNNZ_) atomicAdd(&cnt[NE_ + NV_ + sent_cols[i]], 1);
}

__global__ __launch_bounds__(256) void scanA_kernel(const int* __restrict__ cnt,
                                                    int* __restrict__ bsum) {
    int blk = blockIdx.x, t = threadIdx.x;
    int4 v = reinterpret_cast<const int4*>(cnt)[blk * 256 + t];
    int s = v.x + v.y + v.z + v.w;
    __shared__ int red[256];
    red[t] = s;
    __syncthreads();
    for (int o = 128; o > 0; o >>= 1) {
        if (t < o) red[t] += red[t + o];
        __syncthreads();
    }
    if (t == 0) bsum[blk] = red[0];
}

__global__ __launch_bounds__(64) void scanB_kernel(const int* __restrict__ bsum,
                                                   int* __restrict__ cbase) {
    if (threadIdx.x == 0) {
        int run = 0;
        for (int c = 0; c < SCAN_NCH; ++c) {
            if (c == SEG1_CH || c == SEG2_CH) run = 0;
            cbase[c] = run;
            run += bsum[c];
        }
    }
}

__global__ __launch_bounds__(256) void scanC_kernel(const int* __restrict__ cnt,
                                                    const int* __restrict__ cbase,
                                                    int* __restrict__ rowptr_e,
                                                    int* __restrict__ rowptr_v,
                                                    int* __restrict__ rowptr_s,
                                                    int* __restrict__ fill) {
    int blk = blockIdx.x, t = threadIdx.x;
    int gi = blk * 1024 + t * 4;
    int4 v = reinterpret_cast<const int4*>(cnt)[blk * 256 + t];
    int s0 = v.x, s1 = s0 + v.y, s2 = s1 + v.z, s3 = s2 + v.w;
    __shared__ int part[256];
    part[t] = s3;
    __syncthreads();
    for (int o = 1; o < 256; o <<= 1) {
        int a = (t >= o) ? part[t - o] : 0;
        __syncthreads();
        part[t] += a;
        __syncthreads();
    }
    int excl = (t > 0 ? part[t - 1] : 0) + cbase[blk];
    int4 e;
    e.x = excl; e.y = excl + s0; e.z = excl + s1; e.w = excl + s2;
    int* rp; int li;
    if (blk < SEG1_CH)      { rp = rowptr_e; li = gi; }
    else if (blk < SEG2_CH) { rp = rowptr_v; li = gi - NE_; }
    else                    { rp = rowptr_s; li = gi - NE_ - NV_; }
    rp[li + 0] = e.x; rp[li + 1] = e.y; rp[li + 2] = e.z; rp[li + 3] = e.w;
    reinterpret_cast<int4*>(fill)[blk * 256 + t] = e;
    if (t == 255) {
        int tot = excl + s3;
        if (blk == SEG1_CH - 1) rowptr_e[NE_] = tot;
        if (blk == SEG2_CH - 1) rowptr_v[NV_] = tot;
        if (blk == SCAN_NCH - 1) rowptr_s[NE_] = tot;
    }
}

// fused placement; folds deg_e into val_e, deg_v into val_v, x into srcX_e
__global__ __launch_bounds__(256) void place_kernel(const int* __restrict__ inc_rows,
                                                    const int* __restrict__ inc_cols,
                                                    const float* __restrict__ inc_vals,
                                                    const int* __restrict__ sent_rows,
                                                    const int* __restrict__ sent_cols,
                                                    const float* __restrict__ sent_vals,
                                                    const int* __restrict__ x,
                                                    const float* __restrict__ deg_e,
                                                    const float* __restrict__ deg_v,
                                                    int* __restrict__ fill,
                                                    int* __restrict__ srcA_e,
                                                    int* __restrict__ srcX_e,
                                                    float* __restrict__ val_e,
                                                    int* __restrict__ srcA_v,
                                                    float* __restrict__ val_v,
                                                    int* __restrict__ srcA_s,
                                                    float* __restrict__ val_s) {
    int i = blockIdx.x * 256 + threadIdx.x;
    int r = inc_rows[i], c = inc_cols[i];
    float v = inc_vals[i];
    int pe = atomicAdd(&fill[c], 1);
    srcA_e[pe] = r;
    srcX_e[pe] = x[r];
    val_e[pe] = v * deg_e[c];
    int pv = atomicAdd(&fill[NE_ + r], 1);
    srcA_v[pv] = c;
    val_v[pv] = v * deg_v[r];
    if (i < SNNZ_) {
        int ps = atomicAdd(&fill[NE_ + NV_ + sent_cols[i]], 1);
        srcA_s[ps] = sent_rows[i];
        val_s[ps] = sent_vals[i];
    }
}

// ---------------- 256-dim segment gather-sum, bf16 src/dst ---------------------------
// dst[seg][:] = sum_k vals[k]*src[srcidx[k]][:]   (+bias,relu if EPI; + attW dot -> e if ATT)
template <bool EPI, bool ATT>
__global__ __launch_bounds__(256) void gather256_kernel(const int* __restrict__ rowptr,
                                                        const int* __restrict__ srcidx,
                                                        const float* __restrict__ svals,
                                                        const u16* __restrict__ src,
                                                        const float* __restrict__ bias,
                                                        u16* __restrict__ dst, int nseg,
                                                        const float* __restrict__ attW,
                                                        const float* __restrict__ attb,
                                                        const float* __restrict__ tfidf,
                                                        float* __restrict__ e) {
    int seg = (blockIdx.x * 256 + threadIdx.x) >> 6;
    int lane = threadIdx.x & 63;
    if (seg >= nseg) return;
    int start = rowptr[seg], end = rowptr[seg + 1];
    float4 acc = make_float4(0.f, 0.f, 0.f, 0.f);
    for (int k = start; k < end; ++k) {
        int r = srcidx[k];
        float v = svals[k];
        ushort4 sv = *reinterpret_cast<const ushort4*>(src + (size_t)r * 256 + lane * 4);
        acc.x += v * bf2f(sv.x); acc.y += v * bf2f(sv.y);
        acc.z += v * bf2f(sv.z); acc.w += v * bf2f(sv.w);
    }
    float4 o = acc;
    if constexpr (EPI) {
        float4 bv = reinterpret_cast<const float4*>(bias)[lane];
        o.x = fmaxf(o.x + bv.x, 0.f); o.y = fmaxf(o.y + bv.y, 0.f);
        o.z = fmaxf(o.z + bv.z, 0.f); o.w = fmaxf(o.w + bv.w, 0.f);
    }
    ushort4 o4;
    o4.x = f2bf(o.x); o4.y = f2bf(o.y); o4.z = f2bf(o.z); o4.w = f2bf(o.w);
    *reinterpret_cast<ushort4*>(dst + (size_t)seg * 256 + lane * 4) = o4;
    if constexpr (ATT) {
        float4 aw = reinterpret_cast<const float4*>(attW)[lane];
        float pe = o.x * aw.x + o.y * aw.y + o.z * aw.z + o.w * aw.w;
#pragma unroll
        for (int off = 32; off > 0; off >>= 1) pe += __shfl_down(pe, off);
        if (lane == 0)
            e[seg] = pe + tfidf[seg * 2] * attW[HID_] + tfidf[seg * 2 + 1] * attW[HID_ + 1]
                     + attb[0];
    }
}

// ---------------- W -> transposed hi/lo bf16 split (both weights, fused) ------------
__global__ __launch_bounds__(256) void wconv_kernel(const float* __restrict__ W1,
                                                    const float* __restrict__ W2,
                                                    u16* __restrict__ Wt1h, u16* __restrict__ Wt1l,
                                                    u16* __restrict__ Wt2h, u16* __restrict__ Wt2l) {
    int idx = blockIdx.x * 256 + threadIdx.x;
    const float* W; u16 *Wh, *Wl; int K, KP;
    if (idx < 256 * 320) { W = W1; Wh = Wt1h; Wl = Wt1l; K = D_; KP = 320; }
    else { idx -= 256 * 320; if (idx >= 256 * 256) return;
           W = W2; Wh = Wt2h; Wl = Wt2l; K = HID_; KP = 256; }
    int n = idx & 255;
    int k = idx >> 8;
    float v = (k < K) ? W[(size_t)k * HID_ + n] : 0.f;
    u16 hi = f2bf(v);
    u16 lo = f2bf(v - bf2f(hi));
    Wh[(size_t)n * KP + k] = hi;
    Wl[(size_t)n * KP + k] = lo;
}

// ---------------- MFMA GEMM, full-N tile 64x256: C = A @ Wt^T -----------------------
// SPLIT_A: A f32, hi/lo split (3 MFMA); else A bf16 (2 MFMA). EPI: C=relu(acc+bias).
// EAp (SPLIT_A only): EA[row] = A[row][:K] . attWA   (free f32 dot during staging)
// ATT: e[row] = relu-ed C[row][:] . attW[:256] + tfidf-terms (epilogue reduce)
template <bool SPLIT_A, bool EPI, bool ATT>
__global__ __launch_bounds__(256) void gemm_mfma_kernel(const void* __restrict__ Av,
                                                        int M, int K, int Ks,
                                                        const u16* __restrict__ Bth,
                                                        const u16* __restrict__ Btl, int bstride,
                                                        const float* __restrict__ bias,
                                                        void* __restrict__ Cv,
                                                        const float* __restrict__ attWA,
                                                        float* __restrict__ EAp,
                                                        const float* __restrict__ attW,
                                                        const float* __restrict__ attb,
                                                        const float* __restrict__ tfidf,
                                                        float* __restrict__ e) {
    __shared__ __align__(16) u16 Ah[64 * 32];
    __shared__ __align__(16) u16 Al[64 * 32];
    __shared__ __align__(16) u16 Bh[256 * 32];
    __shared__ __align__(16) u16 Bl[256 * 32];
    int tid = threadIdx.x;
    int bm0 = blockIdx.x * 64;
    int w = tid >> 6, l = tid & 63;
    int srow = tid >> 2;
    int skbp = tid & 3;
    int skbl = skbp ^ ((srow >> 1) & 3);
    int arow = bm0 + srow; if (arow >= M) arow = M - 1;
    int sdst = srow * 32 + skbp * 8;
    int frow = w * 16 + (l & 15);
    int akbp = (l >> 4) ^ ((frow >> 1) & 3);

    f32x4 acc[16] = {};
    float ea = 0.f;
    int nkt = (K + 31) / 32;
    for (int kt = 0; kt < nkt; ++kt) {
        if (kt) __syncthreads();
        int kbase = kt * 32 + skbl * 8;
        if constexpr (SPLIT_A) {
            const float* Arow = (const float*)Av + (size_t)arow * Ks;
            float av[8];
            if (kbase + 8 <= K) {
                float4 v0 = *reinterpret_cast<const float4*>(Arow + kbase);
                float4 v1 = *reinterpret_cast<const float4*>(Arow + kbase + 4);
                av[0] = v0.x; av[1] = v0.y; av[2] = v0.z; av[3] = v0.w;
                av[4] = v1.x; av[5] = v1.y; av[6] = v1.z; av[7] = v1.w;
            } else {
#pragma unroll
                for (int ee = 0; ee < 8; ++ee) {
                    int kk = kbase + ee;
                    av[ee] = (kk < K) ? Arow[kk] : 0.f;
                }
            }
            if (EAp) {
#pragma unroll
                for (int ee = 0; ee < 8; ++ee) {
                    int kk = kbase + ee;
                    ea += av[ee] * ((kk < K) ? attWA[kk] : 0.f);
                }
            }
            short8 h8, l8;
#pragma unroll
            for (int ee = 0; ee < 8; ++ee) {
                u16 hi = f2bf(av[ee]);
                h8[ee] = (short)hi;
                l8[ee] = (short)f2bf(av[ee] - bf2f(hi));
            }
            *(short8*)&Ah[sdst] = h8;
            *(short8*)&Al[sdst] = l8;
        } else {
            const u16* Arow = (const u16*)Av + (size_t)arow * Ks;
            *(short8*)&Ah[sdst] = *(const short8*)(Arow + kbase);
        }
#pragma unroll
        for (int i = 0; i < 4; ++i) {
            int br = i * 64 + srow;
            int bkl = skbp ^ ((br >> 1) & 3);
            *(short8*)&Bh[br * 32 + skbp * 8] =
                *(const short8*)(Bth + (size_t)br * bstride + kt * 32 + bkl * 8);
            *(short8*)&Bl[br * 32 + skbp * 8] =
                *(const short8*)(Btl + (size_t)br * bstride + kt * 32 + bkl * 8);
        }
        __syncthreads();
        short8 ah = *(const short8*)&Ah[frow * 32 + akbp * 8];
        short8 al;
        if constexpr (SPLIT_A) al = *(const short8*)&Al[frow * 32 + akbp * 8];
#pragma unroll
        for (int nt = 0; nt < 16; ++nt) {
            int nrow = nt * 16 + (l & 15);
            int bkbp = (l >> 4) ^ ((nrow >> 1) & 3);
            short8 tbh = *(const short8*)&Bh[nrow * 32 + bkbp * 8];
            short8 tbl = *(const short8*)&Bl[nrow * 32 + bkbp * 8];
            acc[nt] = __builtin_amdgcn_mfma_f32_16x16x32_bf16(ah, tbh, acc[nt], 0, 0, 0);
            if constexpr (SPLIT_A)
                acc[nt] = __builtin_amdgcn_mfma_f32_16x16x32_bf16(al, tbh, acc[nt], 0, 0, 0);
            acc[nt] = __builtin_amdgcn_mfma_f32_16x16x32_bf16(ah, tbl, acc[nt], 0, 0, 0);
        }
    }
    if constexpr (SPLIT_A) {
        if (EAp) {
            ea += __shfl_xor(ea, 1);
            ea += __shfl_xor(ea, 2);
            if ((tid & 3) == 0 && bm0 + srow < M) EAp[bm0 + srow] = ea;
        }
    }
#pragma unroll
    for (int r = 0; r < 4; ++r) {
        int row = bm0 + w * 16 + (l >> 4) * 4 + r;
        if (row >= M) continue;
        float er = 0.f;
#pragma unroll
        for (int nt = 0; nt < 16; ++nt) {
            int col = nt * 16 + (l & 15);
            float v = acc[nt][r];
            if constexpr (EPI) {
                v = v + bias[col];
                v = v > 0.f ? v : 0.f;
            }
            if constexpr (ATT) er += v * attW[col];
            ((u16*)Cv)[(size_t)row * 256 + col] = f2bf(v);
        }
        if constexpr (ATT) {
            er += __shfl_xor(er, 1);
            er += __shfl_xor(er, 2);
            er += __shfl_xor(er, 4);
            er += __shfl_xor(er, 8);
            if ((l & 15) == 0)
                e[row] = er + tfidf[row * 2] * attW[HID_] + tfidf[row * 2 + 1] * attW[HID_ + 1]
                         + attb[0];
        }
    }
}

// ---------------- fused pool: per-graph softmax + weighted-sum + max ----------------
// grid (B, dim-chunks of 64); block 256 = 4 waves, each wave covers 128 nodes.
// L0: h = f32 emb rows via x[], logits from EA; else h bf16, logits from e[].
template <bool L0>
__global__ __launch_bounds__(256) void pool_kernel(const void* __restrict__ h, int dim,
                                                   int stride,
                                                   const int* __restrict__ x,
                                                   const float* __restrict__ EA,
                                                   const float* __restrict__ e,
                                                   const float* __restrict__ tfidf,
                                                   const float* __restrict__ attW,
                                                   const float* __restrict__ attb,
                                                   float* __restrict__ p) {
    int b = blockIdx.x, c = blockIdx.y;
    int t = threadIdx.x;
    __shared__ float sw[N_];
    __shared__ int rows[N_];
    __shared__ float red[256];
    __shared__ float ps_[4][64], pm_[4][64];
    int n0 = b * N_ + t, n1 = n0 + 256;
    float ev0, ev1;
    int r0, r1;
    if constexpr (L0) {
        r0 = x[n0]; r1 = x[n1];
        float a0 = attW[D_], a1 = attW[D_ + 1], ab = attb[0];
        ev0 = EA[r0] + tfidf[n0 * 2] * a0 + tfidf[n0 * 2 + 1] * a1 + ab;
        ev1 = EA[r1] + tfidf[n1 * 2] * a0 + tfidf[n1 * 2 + 1] * a1 + ab;
    } else {
        r0 = n0; r1 = n1;
        ev0 = e[n0]; ev1 = e[n1];
    }
    rows[t] = r0; rows[t + 256] = r1;
    red[t] = fmaxf(ev0, ev1);
    __syncthreads();
    for (int s = 128; s > 0; s >>= 1) {
        if (t < s) red[t] = fmaxf(red[t], red[t + s]);
        __syncthreads();
    }
    float mx = red[0];
    __syncthreads();
    float w0 = expf(ev0 - mx), w1 = expf(ev1 - mx);
    red[t] = w0 + w1;
    __syncthreads();
    for (int s = 128; s > 0; s >>= 1) {
        if (t < s) red[t] += red[t + s];
        __syncthreads();
    }
    float inv = 1.f / (red[0] + 1e-10f);
    sw[t] = w0 * inv; sw[t + 256] = w1 * inv;
    __syncthreads();
    int lane = t & 63, wv = t >> 6;
    int d = c * 64 + lane;
    bool act = d < dim;
    float s = 0.f, m = -3.4e38f;
    for (int i = 0; i < 128; ++i) {
        int nl = wv * 128 + i;
        float xv = 0.f;
        if (act) {
            if constexpr (L0) xv = ((const float*)h)[(size_t)rows[nl] * stride + d];
            else              xv = bf2f(((const u16*)h)[(size_t)rows[nl] * stride + d]);
        }
        s += sw[nl] * xv;
        m = fmaxf(m, xv);
    }
    ps_[wv][lane] = s; pm_[wv][lane] = m;
    __syncthreads();
    if (wv == 0 && act) {
        float S = ps_[0][lane] + ps_[1][lane] + ps_[2][lane] + ps_[3][lane];
        float M = fmaxf(fmaxf(pm_[0][lane], pm_[1][lane]), fmaxf(pm_[2][lane], pm_[3][lane]));
        p[(size_t)b * 2 * dim + d] = S;
        p[(size_t)b * 2 * dim + dim + d] = M;
    }
}

// ---------------- final prediction (parallel GEMV, 256 thr/graph) --------------------
__global__ __launch_bounds__(256) void final_kernel(const float* __restrict__ p0,
                                                    const float* __restrict__ p1,
                                                    const float* __restrict__ p2,
                                                    const float* __restrict__ pW0,
                                                    const float* __restrict__ pb0,
                                                    const float* __restrict__ pW1,
                                                    const float* __restrict__ pb1,
                                                    const float* __restrict__ pW2,
                                                    const float* __restrict__ pb2,
                                                    float* __restrict__ out) {
    int b = blockIdx.x;
    int t = threadIdx.x;
    int lane = t & 63, wv = t >> 6;
    float acc[NC_] = {};
    for (int k = t; k < 2 * D_; k += 256) {
        float pv = p0[(size_t)b * 2 * D_ + k];
        const float* wp = pW0 + (size_t)k * NC_;
#pragma unroll
        for (int c = 0; c < NC_; ++c) acc[c] += pv * wp[c];
    }
    for (int k = t; k < 2 * HID_; k += 256) {
        float pv = p1[(size_t)b * 2 * HID_ + k];
        const float* wp = pW1 + (size_t)k * NC_;
#pragma unroll
        for (int c = 0; c < NC_; ++c) acc[c] += pv * wp[c];
    }
    for (int k = t; k < 2 * HID_; k += 256) {
        float pv = p2[(size_t)b * 2 * HID_ + k];
        const float* wp = pW2 + (size_t)k * NC_;
#pragma unroll
        for (int c = 0; c < NC_; ++c) acc[c] += pv * wp[c];
    }
    __shared__ float red[4][NC_];
#pragma unroll
    for (int c = 0; c < NC_; ++c) {
        float s = acc[c];
#pragma unroll
        for (int off = 32; off > 0; off >>= 1) s += __shfl_down(s, off);
        if (lane == 0) red[wv][c] = s;
    }
    __syncthreads();
    if (t < NC_) {
        float s = red[0][t] + red[1][t] + red[2][t] + red[3][t];
        out[b * NC_ + t] = s + pb0[t] + pb1[t] + pb2[t];
    }
}

extern "C" void kernel_launch(void* const* d_in, const int* in_sizes, int n_in,
                              void* d_out, int out_size, void* d_ws, size_t ws_size,
                              hipStream_t stream) {
    const int*   x         = (const int*)d_in[0];
    const int*   inc_rows  = (const int*)d_in[1];
    const int*   inc_cols  = (const int*)d_in[2];
    const float* inc_vals  = (const float*)d_in[3];
    const int*   sent_rows = (const int*)d_in[4];
    const int*   sent_cols = (const int*)d_in[5];
    const float* sent_vals = (const float*)d_in[6];
    const float* deg_v     = (const float*)d_in[7];
    const float* deg_e     = (const float*)d_in[8];
    const float* tf_idf = (const float*)d_in[11];
    const float* emb    = (const float*)d_in[12];
    const float* W1 = (const float*)d_in[13];
    const float* b1 = (const float*)d_in[14];
    const float* W2 = (const float*)d_in[15];
    const float* b2 = (const float*)d_in[16];
    const float* attW0 = (const float*)d_in[17];
    const float* attb0 = (const float*)d_in[18];
    const float* attW1 = (const float*)d_in[19];
    const float* attb1 = (const float*)d_in[20];
    const float* attW2 = (const float*)d_in[21];
    const float* attb2 = (const float*)d_in[22];
    const float* pW0 = (const float*)d_in[23];
    const float* pb0 = (const float*)d_in[24];
    const float* pW1 = (const float*)d_in[25];
    const float* pb1 = (const float*)d_in[26];
    const float* pW2 = (const float*)d_in[27];
    const float* pb2 = (const float*)d_in[28];
    float* out = (float*)d_out;

    // workspace layout
    char* ws = (char*)d_ws;
    size_t off = 0;
    auto alloc = [&](size_t bytes) {
        void* p = ws + off;
        off += (bytes + 255) & ~(size_t)255;
        return p;
    };
    u16* EW = (u16*)alloc((size_t)VOCAB_ * HID_ * sizeof(u16)); // emb @ W1, bf16
    u16* hv = (u16*)alloc((size_t)NV_ * HID_ * sizeof(u16));
    u16* m  = (u16*)alloc((size_t)NE_ * HID_ * sizeof(u16));
    u16* m2 = (u16*)alloc((size_t)NE_ * HID_ * sizeof(u16));
    u16* h1 = (u16*)alloc((size_t)NV_ * HID_ * sizeof(u16));
    u16* h2 = (u16*)alloc((size_t)NV_ * HID_ * sizeof(u16));
    u16* Wt1h = (u16*)alloc((size_t)HID_ * 320 * sizeof(u16));
    u16* Wt1l = (u16*)alloc((size_t)HID_ * 320 * sizeof(u16));
    u16* Wt2h = (u16*)alloc((size_t)HID_ * 256 * sizeof(u16));
    u16* Wt2l = (u16*)alloc((size_t)HID_ * 256 * sizeof(u16));
    float* EA = (float*)alloc((size_t)VOCAB_ * sizeof(float));  // emb @ attW0[:300]
    float* e  = (float*)alloc((size_t)NV_ * sizeof(float));
    float* p0 = (float*)alloc((size_t)B_ * 2 * D_ * sizeof(float));
    float* p1 = (float*)alloc((size_t)B_ * 2 * HID_ * sizeof(float));
    float* p2 = (float*)alloc((size_t)B_ * 2 * HID_ * sizeof(float));
    // CSR structures
    int* cnt  = (int*)alloc((size_t)SCAN_TOT * sizeof(int));  // [cnt_e|cnt_v|cnt_s]
    int* fill = (int*)alloc((size_t)SCAN_TOT * sizeof(int));
    int* rowptr_e = (int*)alloc((size_t)(NE_ + 1) * sizeof(int));
    int* rowptr_v = (int*)alloc((size_t)(NV_ + 1) * sizeof(int));
    int* rowptr_s = (int*)alloc((size_t)(NE_ + 1) * sizeof(int));
    int* bsum  = (int*)alloc((size_t)SCAN_NCH * sizeof(int));
    int* cbase = (int*)alloc((size_t)SCAN_NCH * sizeof(int));
    int*   srcA_e = (int*)  alloc((size_t)NNZ_ * sizeof(int));
    int*   srcX_e = (int*)  alloc((size_t)NNZ_ * sizeof(int));
    float* val_e  = (float*)alloc((size_t)NNZ_ * sizeof(float));
    int*   srcA_v = (int*)  alloc((size_t)NNZ_ * sizeof(int));
    float* val_v  = (float*)alloc((size_t)NNZ_ * sizeof(float));
    int*   srcA_s = (int*)  alloc((size_t)SNNZ_ * sizeof(int));
    float* val_s  = (float*)alloc((size_t)SNNZ_ * sizeof(float));

    // ---- build CSR (fused hist / scan / fused place with deg folding) ----
    hipMemsetAsync(cnt, 0, (size_t)SCAN_TOT * sizeof(int), stream);
    hist_kernel<<<NNZ_ / 256, 256, 0, stream>>>(inc_rows, inc_cols, sent_cols, cnt);
    scanA_kernel<<<SCAN_NCH, 256, 0, stream>>>(cnt, bsum);
    scanB_kernel<<<1, 64, 0, stream>>>(bsum, cbase);
    scanC_kernel<<<SCAN_NCH, 256, 0, stream>>>(cnt, cbase, rowptr_e, rowptr_v, rowptr_s, fill);
    place_kernel<<<NNZ_ / 256, 256, 0, stream>>>(inc_rows, inc_cols, inc_vals,
                                                 sent_rows, sent_cols, sent_vals,
                                                 x, deg_e, deg_v, fill,
                                                 srcA_e, srcX_e, val_e,
                                                 srcA_v, val_v, srcA_s, val_s);

    // ---- weight conversion (both layers, one launch) ----
    wconv_kernel<<<(256 * 320 + 256 * 256 + 255) / 256, 256, 0, stream>>>(
        W1, W2, Wt1h, Wt1l, Wt2h, Wt2l);

    // ---- EW = emb @ W1 (bf16 out) + EA = emb @ attW0 (free, f32) ----
    gemm_mfma_kernel<true, false, false><<<(VOCAB_ + 63) / 64, 256, 0, stream>>>(
        emb, VOCAB_, D_, D_, Wt1h, Wt1l, 320, nullptr, EW,
        attW0, EA, nullptr, nullptr, nullptr, nullptr);

    // ---- pool layer 0 (softmax from EA, raw emb features) ----
    {
        dim3 g(B_, (D_ + 63) / 64);
        pool_kernel<true><<<g, 256, 0, stream>>>(emb, D_, D_, x, EA, nullptr,
                                                 tf_idf, attW0, attb0, p0);
    }

    // ---- layer 1 sparse chain @ dim 256 (deg folded into vals) ----
    gather256_kernel<false, false><<<NE_ / 4, 256, 0, stream>>>(
        rowptr_e, srcX_e, val_e, EW, nullptr, m, NE_, nullptr, nullptr, nullptr, nullptr);
    gather256_kernel<false, false><<<NE_ / 4, 256, 0, stream>>>(
        rowptr_s, srcA_s, val_s, m, nullptr, m2, NE_, nullptr, nullptr, nullptr, nullptr);
    gather256_kernel<true, true><<<NV_ / 4, 256, 0, stream>>>(
        rowptr_v, srcA_v, val_v, m2, b1, h1, NV_, attW1, attb1, tf_idf, e);

    // ---- pool layer 1 ----
    {
        dim3 g(B_, HID_ / 64);
        pool_kernel<false><<<g, 256, 0, stream>>>(h1, HID_, HID_, nullptr, nullptr, e,
                                                  tf_idf, attW1, attb1, p1);
    }

    // ---- layer 2 ----
    gather256_kernel<false, false><<<NE_ / 4, 256, 0, stream>>>(
        rowptr_e, srcA_e, val_e, h1, nullptr, m, NE_, nullptr, nullptr, nullptr, nullptr);
    gather256_kernel<false, false><<<NE_ / 4, 256, 0, stream>>>(
        rowptr_s, srcA_s, val_s, m, nullptr, m2, NE_, nullptr, nullptr, nullptr, nullptr);
    gather256_kernel<false, false><<<NV_ / 4, 256, 0, stream>>>(
        rowptr_v, srcA_v, val_v, m2, nullptr, hv, NV_, nullptr, nullptr, nullptr, nullptr);
    // h2 = relu(hv @ W2 + b2) (deg_v already in hv) + e2 in epilogue
    gemm_mfma_kernel<false, true, true><<<NV_ / 64, 256, 0, stream>>>(
        hv, NV_, HID_, HID_, Wt2h, Wt2l, 256, b2, h2,
        nullptr, nullptr, attW2, attb2, tf_idf, e);

    // ---- pool layer 2 ----
    {
        dim3 g(B_, HID_ / 64);
        pool_kernel<false><<<g, 256, 0, stream>>>(h2, HID_, HID_, nullptr, nullptr, e,
                                                  tf_idf, attW2, attb2, p2);
    }

    // ---- final linear ----
    final_kernel<<<B_, 256, 0, stream>>>(p0, p1, p2, pW0, pb0, pW1, pb1, pW2, pb2, out);
}

// Round 10
// 346.664 us; speedup vs baseline: 1.1177x; 1.1177x over previous
//
#include <hip/hip_runtime.h>
#include <cstddef>

#define B_   64
#define N_   512
#define NV_  32768
#define NE_  8192
#define NNZ_ 262144
#define SNNZ_ 24576
#define D_   300
#define HID_ 256
#define NC_  10
#define VOCAB_ 30000
#define PCHUNK 8
#define PVN (N_ / PCHUNK)   // 64 nodes per pool chunk

#define SCAN_TOT (NE_ + NV_ + NE_)      // 49152 counts, contiguous [cnt_e|cnt_v|cnt_s]
#define SCAN_NCH (SCAN_TOT / 1024)      // 48 chunks
#define SEG1_CH  (NE_ / 1024)           // 8  (start of cnt_v chunks)
#define SEG2_CH  ((NE_ + NV_) / 1024)   // 40 (start of cnt_s chunks)

using u16 = unsigned short;
typedef __attribute__((ext_vector_type(8))) short short8;
typedef __attribute__((ext_vector_type(4))) float f32x4;

__device__ __forceinline__ float bf2f(u16 v) {
    union { unsigned int u; float f; } uf;
    uf.u = ((unsigned int)v) << 16;
    return uf.f;
}
__device__ __forceinline__ u16 f2bf(float f) {
    union { float f; unsigned int u; } uf; uf.f = f;
    unsigned int u = uf.u;
    unsigned int r = u + 0x7fffu + ((u >> 16) & 1u);
    return (u16)(r >> 16);
}

// ---------------- CSR build ----------------------------------------------------------
__global__ __launch_bounds__(256) void hist_kernel(const int* __restrict__ inc_rows,
                                                   const int* __restrict__ inc_cols,
                                                   const int* __restrict__ sent_cols,
                                                   int* __restrict__ cnt) {
    int i = blockIdx.x * 256 + threadIdx.x;
    atomicAdd(&cnt[inc_cols[i]], 1);
    atomicAdd(&cnt[NE_ + inc_rows[i]], 1);
    if (i < SNNZ_) atomicAdd(&cnt[NE_ + NV_ + sent_cols[i]], 1);
}

__global__ __launch_bounds__(256) void scanA_kernel(const int* __restrict__ cnt,
                                                    int* __restrict__ bsum) {
    int blk = blockIdx.x, t = threadIdx.x;
    int4 v = reinterpret_cast<const int4*>(cnt)[blk * 256 + t];
    int s = v.x + v.y + v.z + v.w;
    __shared__ int red[256];
    red[t] = s;
    __syncthreads();
    for (int o = 128; o > 0; o >>= 1) {
        if (t < o) red[t] += red[t + o];
        __syncthreads();
    }
    if (t == 0) bsum[blk] = red[0];
}

__global__ __launch_bounds__(64) void scanB_kernel(const int* __restrict__ bsum,
                                                   int* __restrict__ cbase) {
    if (threadIdx.x == 0) {
        int run = 0;
        for (int c = 0; c < SCAN_NCH; ++c) {
            if (c == SEG1_CH || c == SEG2_CH) run = 0;
            cbase[c] = run;
            run += bsum[c];
        }
    }
}

__global__ __launch_bounds__(256) void scanC_kernel(const int* __restrict__ cnt,
                                                    const int* __restrict__ cbase,
                                                    int* __restrict__ rowptr_e,
                                                    int* __restrict__ rowptr_v,
                                                    int* __restrict__ rowptr_s,
                                                    int* __restrict__ fill) {
    int blk = blockIdx.x, t = threadIdx.x;
    int gi = blk * 1024 + t * 4;
    int4 v = reinterpret_cast<const int4*>(cnt)[blk * 256 + t];
    int s0 = v.x, s1 = s0 + v.y, s2 = s1 + v.z, s3 = s2 + v.w;
    __shared__ int part[256];
    part[t] = s3;
    __syncthreads();
    for (int o = 1; o < 256; o <<= 1) {
        int a = (t >= o) ? part[t - o] : 0;
        __syncthreads();
        part[t] += a;
        __syncthreads();
    }
    int excl = (t > 0 ? part[t - 1] : 0) + cbase[blk];
    int4 e;
    e.x = excl; e.y = excl + s0; e.z = excl + s1; e.w = excl + s2;
    int* rp; int li;
    if (blk < SEG1_CH)      { rp = rowptr_e; li = gi; }
    else if (blk < SEG2_CH) { rp = rowptr_v; li = gi - NE_; }
    else                    { rp = rowptr_s; li = gi - NE_ - NV_; }
    rp[li + 0] = e.x; rp[li + 1] = e.y; rp[li + 2] = e.z; rp[li + 3] = e.w;
    reinterpret_cast<int4*>(fill)[blk * 256 + t] = e;
    if (t == 255) {
        int tot = excl + s3;
        if (blk == SEG1_CH - 1) rowptr_e[NE_] = tot;
        if (blk == SEG2_CH - 1) rowptr_v[NV_] = tot;
        if (blk == SCAN_NCH - 1) rowptr_s[NE_] = tot;
    }
}

__global__ __launch_bounds__(256) void place_kernel(const int* __restrict__ inc_rows,
                                                    const int* __restrict__ inc_cols,
                                                    const float* __restrict__ inc_vals,
                                                    const int* __restrict__ sent_rows,
                                                    const int* __restrict__ sent_cols,
                                                    const float* __restrict__ sent_vals,
                                                    const int* __restrict__ x,
                                                    const float* __restrict__ deg_e,
                                                    const float* __restrict__ deg_v,
                                                    int* __restrict__ fill,
                                                    int* __restrict__ srcA_e,
                                                    int* __restrict__ srcX_e,
                                                    float* __restrict__ val_e,
                                                    int* __restrict__ srcA_v,
                                                    float* __restrict__ val_v,
                                                    int* __restrict__ srcA_s,
                                                    float* __restrict__ val_s) {
    int i = blockIdx.x * 256 + threadIdx.x;
    int r = inc_rows[i], c = inc_cols[i];
    float v = inc_vals[i];
    int pe = atomicAdd(&fill[c], 1);
    srcA_e[pe] = r;
    srcX_e[pe] = x[r];
    val_e[pe] = v * deg_e[c];
    int pv = atomicAdd(&fill[NE_ + r], 1);
    srcA_v[pv] = c;
    val_v[pv] = v * deg_v[r];
    if (i < SNNZ_) {
        int ps = atomicAdd(&fill[NE_ + NV_ + sent_cols[i]], 1);
        srcA_s[ps] = sent_rows[i];
        val_s[ps] = sent_vals[i];
    }
}

// ---------------- 256-dim segment gather-sum, bf16 src/dst ---------------------------
template <bool EPI, bool ATT>
__global__ __launch_bounds__(256) void gather256_kernel(const int* __restrict__ rowptr,
                                                        const int* __restrict__ srcidx,
                                                        const float* __restrict__ svals,
                                                        const u16* __restrict__ src,
                                                        const float* __restrict__ bias,
                                                        u16* __restrict__ dst, int nseg,
                                                        const float* __restrict__ attW,
                                                        const float* __restrict__ attb,
                                                        const float* __restrict__ tfidf,
                                                        float* __restrict__ e) {
    int seg = (blockIdx.x * 256 + threadIdx.x) >> 6;
    int lane = threadIdx.x & 63;
    if (seg >= nseg) return;
    int start = rowptr[seg], end = rowptr[seg + 1];
    float4 acc = make_float4(0.f, 0.f, 0.f, 0.f);
    for (int k = start; k < end; ++k) {
        int r = srcidx[k];
        float v = svals[k];
        ushort4 sv = *reinterpret_cast<const ushort4*>(src + (size_t)r * 256 + lane * 4);
        acc.x += v * bf2f(sv.x); acc.y += v * bf2f(sv.y);
        acc.z += v * bf2f(sv.z); acc.w += v * bf2f(sv.w);
    }
    float4 o = acc;
    if constexpr (EPI) {
        float4 bv = reinterpret_cast<const float4*>(bias)[lane];
        o.x = fmaxf(o.x + bv.x, 0.f); o.y = fmaxf(o.y + bv.y, 0.f);
        o.z = fmaxf(o.z + bv.z, 0.f); o.w = fmaxf(o.w + bv.w, 0.f);
    }
    ushort4 o4;
    o4.x = f2bf(o.x); o4.y = f2bf(o.y); o4.z = f2bf(o.z); o4.w = f2bf(o.w);
    *reinterpret_cast<ushort4*>(dst + (size_t)seg * 256 + lane * 4) = o4;
    if constexpr (ATT) {
        float4 aw = reinterpret_cast<const float4*>(attW)[lane];
        float pe = o.x * aw.x + o.y * aw.y + o.z * aw.z + o.w * aw.w;
#pragma unroll
        for (int off = 32; off > 0; off >>= 1) pe += __shfl_down(pe, off);
        if (lane == 0)
            e[seg] = pe + tfidf[seg * 2] * attW[HID_] + tfidf[seg * 2 + 1] * attW[HID_ + 1]
                     + attb[0];
    }
}

// ---------------- W -> transposed hi/lo bf16 split (both weights, fused) ------------
__global__ __launch_bounds__(256) void wconv_kernel(const float* __restrict__ W1,
                                                    const float* __restrict__ W2,
                                                    u16* __restrict__ Wt1h, u16* __restrict__ Wt1l,
                                                    u16* __restrict__ Wt2h, u16* __restrict__ Wt2l) {
    int idx = blockIdx.x * 256 + threadIdx.x;
    const float* W; u16 *Wh, *Wl; int K, KP;
    if (idx < 256 * 320) { W = W1; Wh = Wt1h; Wl = Wt1l; K = D_; KP = 320; }
    else { idx -= 256 * 320; if (idx >= 256 * 256) return;
           W = W2; Wh = Wt2h; Wl = Wt2l; K = HID_; KP = 256; }
    int n = idx & 255;
    int k = idx >> 8;
    float v = (k < K) ? W[(size_t)k * HID_ + n] : 0.f;
    u16 hi = f2bf(v);
    u16 lo = f2bf(v - bf2f(hi));
    Wh[(size_t)n * KP + k] = hi;
    Wl[(size_t)n * KP + k] = lo;
}

// ---------------- MFMA GEMM, full-N tile 64x256: C = A @ Wt^T -----------------------
template <bool SPLIT_A, bool EPI, bool ATT>
__global__ __launch_bounds__(256) void gemm_mfma_kernel(const void* __restrict__ Av,
                                                        int M, int K, int Ks,
                                                        const u16* __restrict__ Bth,
                                                        const u16* __restrict__ Btl, int bstride,
                                                        const float* __restrict__ bias,
                                                        void* __restrict__ Cv,
                                                        const float* __restrict__ attWA,
                                                        float* __restrict__ EAp,
                                                        const float* __restrict__ attW,
                                                        const float* __restrict__ attb,
                                                        const float* __restrict__ tfidf,
                                                        float* __restrict__ e) {
    __shared__ __align__(16) u16 Ah[64 * 32];
    __shared__ __align__(16) u16 Al[64 * 32];
    __shared__ __align__(16) u16 Bh[256 * 32];
    __shared__ __align__(16) u16 Bl[256 * 32];
    int tid = threadIdx.x;
    int bm0 = blockIdx.x * 64;
    int w = tid >> 6, l = tid & 63;
    int srow = tid >> 2;
    int skbp = tid & 3;
    int skbl = skbp ^ ((srow >> 1) & 3);
    int arow = bm0 + srow; if (arow >= M) arow = M - 1;
    int sdst = srow * 32 + skbp * 8;
    int frow = w * 16 + (l & 15);
    int akbp = (l >> 4) ^ ((frow >> 1) & 3);

    f32x4 acc[16] = {};
    float ea = 0.f;
    int nkt = (K + 31) / 32;
    for (int kt = 0; kt < nkt; ++kt) {
        if (kt) __syncthreads();
        int kbase = kt * 32 + skbl * 8;
        if constexpr (SPLIT_A) {
            const float* Arow = (const float*)Av + (size_t)arow * Ks;
            float av[8];
            if (kbase + 8 <= K) {
                float4 v0 = *reinterpret_cast<const float4*>(Arow + kbase);
                float4 v1 = *reinterpret_cast<const float4*>(Arow + kbase + 4);
                av[0] = v0.x; av[1] = v0.y; av[2] = v0.z; av[3] = v0.w;
                av[4] = v1.x; av[5] = v1.y; av[6] = v1.z; av[7] = v1.w;
            } else {
#pragma unroll
                for (int ee = 0; ee < 8; ++ee) {
                    int kk = kbase + ee;
                    av[ee] = (kk < K) ? Arow[kk] : 0.f;
                }
            }
            if (EAp) {
#pragma unroll
                for (int ee = 0; ee < 8; ++ee) {
                    int kk = kbase + ee;
                    ea += av[ee] * ((kk < K) ? attWA[kk] : 0.f);
                }
            }
            short8 h8, l8;
#pragma unroll
            for (int ee = 0; ee < 8; ++ee) {
                u16 hi = f2bf(av[ee]);
                h8[ee] = (short)hi;
                l8[ee] = (short)f2bf(av[ee] - bf2f(hi));
            }
            *(short8*)&Ah[sdst] = h8;
            *(short8*)&Al[sdst] = l8;
        } else {
            const u16* Arow = (const u16*)Av + (size_t)arow * Ks;
            *(short8*)&Ah[sdst] = *(const short8*)(Arow + kbase);
        }
#pragma unroll
        for (int i = 0; i < 4; ++i) {
            int br = i * 64 + srow;
            int bkl = skbp ^ ((br >> 1) & 3);
            *(short8*)&Bh[br * 32 + skbp * 8] =
                *(const short8*)(Bth + (size_t)br * bstride + kt * 32 + bkl * 8);
            *(short8*)&Bl[br * 32 + skbp * 8] =
                *(const short8*)(Btl + (size_t)br * bstride + kt * 32 + bkl * 8);
        }
        __syncthreads();
        short8 ah = *(const short8*)&Ah[frow * 32 + akbp * 8];
        short8 al;
        if constexpr (SPLIT_A) al = *(const short8*)&Al[frow * 32 + akbp * 8];
#pragma unroll
        for (int nt = 0; nt < 16; ++nt) {
            int nrow = nt * 16 + (l & 15);
            int bkbp = (l >> 4) ^ ((nrow >> 1) & 3);
            short8 tbh = *(const short8*)&Bh[nrow * 32 + bkbp * 8];
            short8 tbl = *(const short8*)&Bl[nrow * 32 + bkbp * 8];
            acc[nt] = __builtin_amdgcn_mfma_f32_16x16x32_bf16(ah, tbh, acc[nt], 0, 0, 0);
            if constexpr (SPLIT_A)
                acc[nt] = __builtin_amdgcn_mfma_f32_16x16x32_bf16(al, tbh, acc[nt], 0, 0, 0);
            acc[nt] = __builtin_amdgcn_mfma_f32_16x16x32_bf16(ah, tbl, acc[nt], 0, 0, 0);
        }
    }
    if constexpr (SPLIT_A) {
        if (EAp) {
            ea += __shfl_xor(ea, 1);
            ea += __shfl_xor(ea, 2);
            if ((tid & 3) == 0 && bm0 + srow < M) EAp[bm0 + srow] = ea;
        }
    }
#pragma unroll
    for (int r = 0; r < 4; ++r) {
        int row = bm0 + w * 16 + (l >> 4) * 4 + r;
        if (row >= M) continue;
        float er = 0.f;
#pragma unroll
        for (int nt = 0; nt < 16; ++nt) {
            int col = nt * 16 + (l & 15);
            float v = acc[nt][r];
            if constexpr (EPI) {
                v = v + bias[col];
                v = v > 0.f ? v : 0.f;
            }
            if constexpr (ATT) er += v * attW[col];
            ((u16*)Cv)[(size_t)row * 256 + col] = f2bf(v);
        }
        if constexpr (ATT) {
            er += __shfl_xor(er, 1);
            er += __shfl_xor(er, 2);
            er += __shfl_xor(er, 4);
            er += __shfl_xor(er, 8);
            if ((l & 15) == 0)
                e[row] = er + tfidf[row * 2] * attW[HID_] + tfidf[row * 2 + 1] * attW[HID_ + 1]
                         + attb[0];
        }
    }
}

// ---------------- pool stage A: per-graph softmax weights ---------------------------
// L0: logits built from EA[x[node]] + tfidf terms; else from e[node].
template <bool L0>
__global__ __launch_bounds__(512) void weights_kernel(const float* __restrict__ e,
                                                      const int* __restrict__ x,
                                                      const float* __restrict__ EA,
                                                      const float* __restrict__ tfidf,
                                                      const float* __restrict__ attWtail,
                                                      const float* __restrict__ attb,
                                                      float* __restrict__ w) {
    int b = blockIdx.x;
    int t = threadIdx.x;
    int node = b * N_ + t;
    float ev;
    if constexpr (L0) {
        ev = EA[x[node]] + tfidf[node * 2] * attWtail[0] + tfidf[node * 2 + 1] * attWtail[1]
             + attb[0];
    } else {
        ev = e[node];
    }
    __shared__ float red[512];
    red[t] = ev;
    __syncthreads();
    for (int s = 256; s > 0; s >>= 1) {
        if (t < s) red[t] = fmaxf(red[t], red[t + s]);
        __syncthreads();
    }
    float mx = red[0];
    __syncthreads();
    float wv = expf(ev - mx);
    red[t] = wv;
    __syncthreads();
    for (int s = 256; s > 0; s >>= 1) {
        if (t < s) red[t] += red[t + s];
        __syncthreads();
    }
    float inv = 1.f / (red[0] + 1e-10f);
    w[node] = wv * inv;
}

// ---------------- pool stage B: partial weighted-sum + max over 64-node chunks ------
template <bool HBF>
__global__ __launch_bounds__(256) void pool_partial_kernel(const void* __restrict__ h, int dim,
                                                           int stride, const int* __restrict__ xidx,
                                                           const float* __restrict__ w,
                                                           float* __restrict__ psum,
                                                           float* __restrict__ pmax) {
    int b = blockIdx.x, c = blockIdx.y;
    __shared__ int rows[PVN];
    __shared__ float wv[PVN];
    int t = threadIdx.x;
    if (t < PVN) {
        int node = b * N_ + c * PVN + t;
        rows[t] = xidx ? xidx[node] : node;
        wv[t] = w[node];
    }
    __syncthreads();
    float s0 = 0.f, s1 = 0.f, m0 = -3.4e38f, m1 = -3.4e38f;
    int d0 = t, d1 = t + 256;
    bool has1 = d1 < dim;
    for (int i = 0; i < PVN; ++i) {
        float ww = wv[i];
        float x0, x1 = 0.f;
        if constexpr (HBF) {
            const u16* hp = (const u16*)h + (size_t)rows[i] * stride;
            x0 = bf2f(hp[d0]);
            if (has1) x1 = bf2f(hp[d1]);
        } else {
            const float* hp = (const float*)h + (size_t)rows[i] * stride;
            x0 = hp[d0];
            if (has1) x1 = hp[d1];
        }
        s0 += ww * x0;
        m0 = fmaxf(m0, x0);
        if (has1) {
            s1 += ww * x1;
            m1 = fmaxf(m1, x1);
        }
    }
    size_t base = ((size_t)b * PCHUNK + c) * dim;
    psum[base + d0] = s0;
    pmax[base + d0] = m0;
    if (has1) {
        psum[base + d1] = s1;
        pmax[base + d1] = m1;
    }
}

// ---------------- pool stage C: combine chunk partials -------------------------------
__global__ __launch_bounds__(256) void pool_combine_kernel(const float* __restrict__ psum,
                                                           const float* __restrict__ pmax,
                                                           int dim, float* __restrict__ p) {
    int b = blockIdx.x;
    for (int d = threadIdx.x; d < dim; d += 256) {
        float s = 0.f, m = -3.4e38f;
        for (int c = 0; c < PCHUNK; ++c) {
            size_t base = ((size_t)b * PCHUNK + c) * dim;
            s += psum[base + d];
            m = fmaxf(m, pmax[base + d]);
        }
        p[(size_t)b * 2 * dim + d] = s;
        p[(size_t)b * 2 * dim + dim + d] = m;
    }
}

// ---------------- final prediction (parallel GEMV, 256 thr/graph) --------------------
__global__ __launch_bounds__(256) void final_kernel(const float* __restrict__ p0,
                                                    const float* __restrict__ p1,
                                                    const float* __restrict__ p2,
                                                    const float* __restrict__ pW0,
                                                    const float* __restrict__ pb0,
                                                    const float* __restrict__ pW1,
                                                    const float* __restrict__ pb1,
                                                    const float* __restrict__ pW2,
                                                    const float* __restrict__ pb2,
                                                    float* __restrict__ out) {
    int b = blockIdx.x;
    int t = threadIdx.x;
    int lane = t & 63, wv = t >> 6;
    float acc[NC_] = {};
    for (int k = t; k < 2 * D_; k += 256) {
        float pv = p0[(size_t)b * 2 * D_ + k];
        const float* wp = pW0 + (size_t)k * NC_;
#pragma unroll
        for (int c = 0; c < NC_; ++c) acc[c] += pv * wp[c];
    }
    for (int k = t; k < 2 * HID_; k += 256) {
        float pv = p1[(size_t)b * 2 * HID_ + k];
        const float* wp = pW1 + (size_t)k * NC_;
#pragma unroll
        for (int c = 0; c < NC_; ++c) acc[c] += pv * wp[c];
    }
    for (int k = t; k < 2 * HID_; k += 256) {
        float pv = p2[(size_t)b * 2 * HID_ + k];
        const float* wp = pW2 + (size_t)k * NC_;
#pragma unroll
        for (int c = 0; c < NC_; ++c) acc[c] += pv * wp[c];
    }
    __shared__ float red[4][NC_];
#pragma unroll
    for (int c = 0; c < NC_; ++c) {
        float s = acc[c];
#pragma unroll
        for (int off = 32; off > 0; off >>= 1) s += __shfl_down(s, off);
        if (lane == 0) red[wv][c] = s;
    }
    __syncthreads();
    if (t < NC_) {
        float s = red[0][t] + red[1][t] + red[2][t] + red[3][t];
        out[b * NC_ + t] = s + pb0[t] + pb1[t] + pb2[t];
    }
}

extern "C" void kernel_launch(void* const* d_in, const int* in_sizes, int n_in,
                              void* d_out, int out_size, void* d_ws, size_t ws_size,
                              hipStream_t stream) {
    const int*   x         = (const int*)d_in[0];
    const int*   inc_rows  = (const int*)d_in[1];
    const int*   inc_cols  = (const int*)d_in[2];
    const float* inc_vals  = (const float*)d_in[3];
    const int*   sent_rows = (const int*)d_in[4];
    const int*   sent_cols = (const int*)d_in[5];
    const float* sent_vals = (const float*)d_in[6];
    const float* deg_v     = (const float*)d_in[7];
    const float* deg_e     = (const float*)d_in[8];
    const float* tf_idf = (const float*)d_in[11];
    const float* emb    = (const float*)d_in[12];
    const float* W1 = (const float*)d_in[13];
    const float* b1 = (const float*)d_in[14];
    const float* W2 = (const float*)d_in[15];
    const float* b2 = (const float*)d_in[16];
    const float* attW0 = (const float*)d_in[17];
    const float* attb0 = (const float*)d_in[18];
    const float* attW1 = (const float*)d_in[19];
    const float* attb1 = (const float*)d_in[20];
    const float* attW2 = (const float*)d_in[21];
    const float* attb2 = (const float*)d_in[22];
    const float* pW0 = (const float*)d_in[23];
    const float* pb0 = (const float*)d_in[24];
    const float* pW1 = (const float*)d_in[25];
    const float* pb1 = (const float*)d_in[26];
    const float* pW2 = (const float*)d_in[27];
    const float* pb2 = (const float*)d_in[28];
    float* out = (float*)d_out;

    // workspace layout
    char* ws = (char*)d_ws;
    size_t off = 0;
    auto alloc = [&](size_t bytes) {
        void* p = ws + off;
        off += (bytes + 255) & ~(size_t)255;
        return p;
    };
    u16* EW = (u16*)alloc((size_t)VOCAB_ * HID_ * sizeof(u16)); // emb @ W1, bf16
    u16* hv = (u16*)alloc((size_t)NV_ * HID_ * sizeof(u16));
    u16* m  = (u16*)alloc((size_t)NE_ * HID_ * sizeof(u16));
    u16* m2 = (u16*)alloc((size_t)NE_ * HID_ * sizeof(u16));
    u16* h1 = (u16*)alloc((size_t)NV_ * HID_ * sizeof(u16));
    u16* h2 = (u16*)alloc((size_t)NV_ * HID_ * sizeof(u16));
    u16* Wt1h = (u16*)alloc((size_t)HID_ * 320 * sizeof(u16));
    u16* Wt1l = (u16*)alloc((size_t)HID_ * 320 * sizeof(u16));
    u16* Wt2h = (u16*)alloc((size_t)HID_ * 256 * sizeof(u16));
    u16* Wt2l = (u16*)alloc((size_t)HID_ * 256 * sizeof(u16));
    float* EA = (float*)alloc((size_t)VOCAB_ * sizeof(float));  // emb @ attW0[:300]
    float* e  = (float*)alloc((size_t)NV_ * sizeof(float));
    float* watt = (float*)alloc((size_t)NV_ * sizeof(float));
    float* psum = (float*)alloc((size_t)B_ * PCHUNK * D_ * sizeof(float));
    float* pmax = (float*)alloc((size_t)B_ * PCHUNK * D_ * sizeof(float));
    float* p0 = (float*)alloc((size_t)B_ * 2 * D_ * sizeof(float));
    float* p1 = (float*)alloc((size_t)B_ * 2 * HID_ * sizeof(float));
    float* p2 = (float*)alloc((size_t)B_ * 2 * HID_ * sizeof(float));
    // CSR structures
    int* cnt  = (int*)alloc((size_t)SCAN_TOT * sizeof(int));  // [cnt_e|cnt_v|cnt_s]
    int* fill = (int*)alloc((size_t)SCAN_TOT * sizeof(int));
    int* rowptr_e = (int*)alloc((size_t)(NE_ + 1) * sizeof(int));
    int* rowptr_v = (int*)alloc((size_t)(NV_ + 1) * sizeof(int));
    int* rowptr_s = (int*)alloc((size_t)(NE_ + 1) * sizeof(int));
    int* bsum  = (int*)alloc((size_t)SCAN_NCH * sizeof(int));
    int* cbase = (int*)alloc((size_t)SCAN_NCH * sizeof(int));
    int*   srcA_e = (int*)  alloc((size_t)NNZ_ * sizeof(int));
    int*   srcX_e = (int*)  alloc((size_t)NNZ_ * sizeof(int));
    float* val_e  = (float*)alloc((size_t)NNZ_ * sizeof(float));
    int*   srcA_v = (int*)  alloc((size_t)NNZ_ * sizeof(int));
    float* val_v  = (float*)alloc((size_t)NNZ_ * sizeof(float));
    int*   srcA_s = (int*)  alloc((size_t)SNNZ_ * sizeof(int));
    float* val_s  = (float*)alloc((size_t)SNNZ_ * sizeof(float));

    // ---- build CSR (fused hist / scan / fused place with deg folding) ----
    hipMemsetAsync(cnt, 0, (size_t)SCAN_TOT * sizeof(int), stream);
    hist_kernel<<<NNZ_ / 256, 256, 0, stream>>>(inc_rows, inc_cols, sent_cols, cnt);
    scanA_kernel<<<SCAN_NCH, 256, 0, stream>>>(cnt, bsum);
    scanB_kernel<<<1, 64, 0, stream>>>(bsum, cbase);
    scanC_kernel<<<SCAN_NCH, 256, 0, stream>>>(cnt, cbase, rowptr_e, rowptr_v, rowptr_s, fill);
    place_kernel<<<NNZ_ / 256, 256, 0, stream>>>(inc_rows, inc_cols, inc_vals,
                                                 sent_rows, sent_cols, sent_vals,
                                                 x, deg_e, deg_v, fill,
                                                 srcA_e, srcX_e, val_e,
                                                 srcA_v, val_v, srcA_s, val_s);

    // ---- weight conversion (both layers, one launch) ----
    wconv_kernel<<<(256 * 320 + 256 * 256 + 255) / 256, 256, 0, stream>>>(
        W1, W2, Wt1h, Wt1l, Wt2h, Wt2l);

    // ---- EW = emb @ W1 (bf16 out) + EA = emb @ attW0 (free, f32) ----
    gemm_mfma_kernel<true, false, false><<<(VOCAB_ + 63) / 64, 256, 0, stream>>>(
        emb, VOCAB_, D_, D_, Wt1h, Wt1l, 320, nullptr, EW,
        attW0, EA, nullptr, nullptr, nullptr, nullptr);

    // ---- pool layer 0 (3-stage; logits from EA) ----
    {
        dim3 pg(B_, PCHUNK);
        weights_kernel<true><<<B_, 512, 0, stream>>>(nullptr, x, EA, tf_idf,
                                                     attW0 + D_, attb0, watt);
        pool_partial_kernel<false><<<pg, 256, 0, stream>>>(emb, D_, D_, x, watt, psum, pmax);
        pool_combine_kernel<<<B_, 256, 0, stream>>>(psum, pmax, D_, p0);
    }

    // ---- layer 1 sparse chain @ dim 256 (deg folded into vals) ----
    gather256_kernel<false, false><<<NE_ / 4, 256, 0, stream>>>(
        rowptr_e, srcX_e, val_e, EW, nullptr, m, NE_, nullptr, nullptr, nullptr, nullptr);
    gather256_kernel<false, false><<<NE_ / 4, 256, 0, stream>>>(
        rowptr_s, srcA_s, val_s, m, nullptr, m2, NE_, nullptr, nullptr, nullptr, nullptr);
    gather256_kernel<true, true><<<NV_ / 4, 256, 0, stream>>>(
        rowptr_v, srcA_v, val_v, m2, b1, h1, NV_, attW1, attb1, tf_idf, e);

    // ---- pool layer 1 ----
    {
        dim3 pg(B_, PCHUNK);
        weights_kernel<false><<<B_, 512, 0, stream>>>(e, nullptr, nullptr, nullptr,
                                                      nullptr, nullptr, watt);
        pool_partial_kernel<true><<<pg, 256, 0, stream>>>(h1, HID_, HID_, nullptr,
                                                          watt, psum, pmax);
        pool_combine_kernel<<<B_, 256, 0, stream>>>(psum, pmax, HID_, p1);
    }

    // ---- layer 2 ----
    gather256_kernel<false, false><<<NE_ / 4, 256, 0, stream>>>(
        rowptr_e, srcA_e, val_e, h1, nullptr, m, NE_, nullptr, nullptr, nullptr, nullptr);
    gather256_kernel<false, false><<<NE_ / 4, 256, 0, stream>>>(
        rowptr_s, srcA_s, val_s, m, nullptr, m2, NE_, nullptr, nullptr, nullptr, nullptr);
    gather256_kernel<false, false><<<NV_ / 4, 256, 0, stream>>>(
        rowptr_v, srcA_v, val_v, m2, nullptr, hv, NV_, nullptr, nullptr, nullptr, nullptr);
    // h2 = relu(hv @ W2 + b2) (deg_v already in hv) + e2 in epilogue
    gemm_mfma_kernel<false, true, true><<<NV_ / 64, 256, 0, stream>>>(
        hv, NV_, HID_, HID_, Wt2h, Wt2l, 256, b2, h2,
        nullptr, nullptr, attW2, attb2, tf_idf, e);

    // ---- pool layer 2 ----
    {
        dim3 pg(B_, PCHUNK);
        weights_kernel<false><<<B_, 512, 0, stream>>>(e, nullptr, nullptr, nullptr,
                                                      nullptr, nullptr, watt);
        pool_partial_kernel<true><<<pg, 256, 0, stream>>>(h2, HID_, HID_, nullptr,
                                                          watt, psum, pmax);
        pool_combine_kernel<<<B_, 256, 0, stream>>>(psum, pmax, HID_, p2);
    }

    // ---- final linear ----
    final_kernel<<<B_, 256, 0, stream>>>(p0, p1, p2, pW0, pb0, pW1, pb1, pW2, pb2, out);
}

// Round 11
// 337.001 us; speedup vs baseline: 1.1498x; 1.0287x over previous
//
#include <hip/hip_runtime.h>
#include <cstddef>

#define B_   64
#define N_   512
#define NV_  32768
#define NE_  8192
#define NNZ_ 262144
#define SNNZ_ 24576
#define D_   300
#define HID_ 256
#define NC_  10
#define VOCAB_ 30000
#define PCHUNK 8
#define PVN (N_ / PCHUNK)   // 64 nodes per pool chunk

#define SCAN_TOT (NE_ + NV_ + NE_)      // 49152 counts, contiguous [cnt_e|cnt_v|cnt_s]
#define SCAN_NCH (SCAN_TOT / 1024)      // 48 chunks
#define SEG1_CH  (NE_ / 1024)           // 8  (start of cnt_v chunks)
#define SEG2_CH  ((NE_ + NV_) / 1024)   // 40 (start of cnt_s chunks)

using u16 = unsigned short;
typedef __attribute__((ext_vector_type(8))) short short8;
typedef __attribute__((ext_vector_type(4))) float f32x4;

__device__ __forceinline__ float bf2f(u16 v) {
    union { unsigned int u; float f; } uf;
    uf.u = ((unsigned int)v) << 16;
    return uf.f;
}
__device__ __forceinline__ u16 f2bf(float f) {
    union { float f; unsigned int u; } uf; uf.f = f;
    unsigned int u = uf.u;
    unsigned int r = u + 0x7fffu + ((u >> 16) & 1u);
    return (u16)(r >> 16);
}

// ---------------- CSR build ----------------------------------------------------------
__global__ __launch_bounds__(256) void hist_kernel(const int* __restrict__ inc_rows,
                                                   const int* __restrict__ inc_cols,
                                                   const int* __restrict__ sent_cols,
                                                   int* __restrict__ cnt) {
    int i = blockIdx.x * 256 + threadIdx.x;
    atomicAdd(&cnt[inc_cols[i]], 1);
    atomicAdd(&cnt[NE_ + inc_rows[i]], 1);
    if (i < SNNZ_) atomicAdd(&cnt[NE_ + NV_ + sent_cols[i]], 1);
}

__global__ __launch_bounds__(256) void scanA_kernel(const int* __restrict__ cnt,
                                                    int* __restrict__ bsum) {
    int blk = blockIdx.x, t = threadIdx.x;
    int4 v = reinterpret_cast<const int4*>(cnt)[blk * 256 + t];
    int s = v.x + v.y + v.z + v.w;
    __shared__ int red[256];
    red[t] = s;
    __syncthreads();
    for (int o = 128; o > 0; o >>= 1) {
        if (t < o) red[t] += red[t + o];
        __syncthreads();
    }
    if (t == 0) bsum[blk] = red[0];
}

__global__ __launch_bounds__(64) void scanB_kernel(const int* __restrict__ bsum,
                                                   int* __restrict__ cbase) {
    if (threadIdx.x == 0) {
        int run = 0;
        for (int c = 0; c < SCAN_NCH; ++c) {
            if (c == SEG1_CH || c == SEG2_CH) run = 0;
            cbase[c] = run;
            run += bsum[c];
        }
    }
}

__global__ __launch_bounds__(256) void scanC_kernel(const int* __restrict__ cnt,
                                                    const int* __restrict__ cbase,
                                                    int* __restrict__ rowptr_e,
                                                    int* __restrict__ rowptr_v,
                                                    int* __restrict__ rowptr_s,
                                                    int* __restrict__ fill) {
    int blk = blockIdx.x, t = threadIdx.x;
    int gi = blk * 1024 + t * 4;
    int4 v = reinterpret_cast<const int4*>(cnt)[blk * 256 + t];
    int s0 = v.x, s1 = s0 + v.y, s2 = s1 + v.z, s3 = s2 + v.w;
    __shared__ int part[256];
    part[t] = s3;
    __syncthreads();
    for (int o = 1; o < 256; o <<= 1) {
        int a = (t >= o) ? part[t - o] : 0;
        __syncthreads();
        part[t] += a;
        __syncthreads();
    }
    int excl = (t > 0 ? part[t - 1] : 0) + cbase[blk];
    int4 e;
    e.x = excl; e.y = excl + s0; e.z = excl + s1; e.w = excl + s2;
    int* rp; int li;
    if (blk < SEG1_CH)      { rp = rowptr_e; li = gi; }
    else if (blk < SEG2_CH) { rp = rowptr_v; li = gi - NE_; }
    else                    { rp = rowptr_s; li = gi - NE_ - NV_; }
    rp[li + 0] = e.x; rp[li + 1] = e.y; rp[li + 2] = e.z; rp[li + 3] = e.w;
    reinterpret_cast<int4*>(fill)[blk * 256 + t] = e;
    if (t == 255) {
        int tot = excl + s3;
        if (blk == SEG1_CH - 1) rowptr_e[NE_] = tot;
        if (blk == SEG2_CH - 1) rowptr_v[NV_] = tot;
        if (blk == SCAN_NCH - 1) rowptr_s[NE_] = tot;
    }
}

// packed placement: e-list = int4{node, x[node], valbits, 0}; v/s-list = int2{idx, valbits}
__global__ __launch_bounds__(256) void place_kernel(const int* __restrict__ inc_rows,
                                                    const int* __restrict__ inc_cols,
                                                    const float* __restrict__ inc_vals,
                                                    const int* __restrict__ sent_rows,
                                                    const int* __restrict__ sent_cols,
                                                    const float* __restrict__ sent_vals,
                                                    const int* __restrict__ x,
                                                    const float* __restrict__ deg_e,
                                                    const float* __restrict__ deg_v,
                                                    int* __restrict__ fill,
                                                    int4* __restrict__ elist,
                                                    int2* __restrict__ vlist,
                                                    int2* __restrict__ slist) {
    int i = blockIdx.x * 256 + threadIdx.x;
    int r = inc_rows[i], c = inc_cols[i];
    float v = inc_vals[i];
    int pe = atomicAdd(&fill[c], 1);
    int4 ee;
    ee.x = r; ee.y = x[r];
    ee.z = __float_as_int(v * deg_e[c]); ee.w = 0;
    elist[pe] = ee;
    int pv = atomicAdd(&fill[NE_ + r], 1);
    int2 vv;
    vv.x = c; vv.y = __float_as_int(v * deg_v[r]);
    vlist[pv] = vv;
    if (i < SNNZ_) {
        int ps = atomicAdd(&fill[NE_ + NV_ + sent_cols[i]], 1);
        int2 ss;
        ss.x = sent_rows[i]; ss.y = __float_as_int(sent_vals[i]);
        slist[ps] = ss;
    }
}

// ---------------- 256-dim segment gather-sum, bf16 src/dst ---------------------------
// MODE 0: int2 list {src, val}; MODE 1: int4 list use .x (node); MODE 2: int4 use .y (x[node])
template <int MODE, bool EPI, bool ATT>
__global__ __launch_bounds__(256) void gather256_kernel(const int* __restrict__ rowptr,
                                                        const void* __restrict__ listv,
                                                        const u16* __restrict__ src,
                                                        const float* __restrict__ bias,
                                                        u16* __restrict__ dst, int nseg,
                                                        const float* __restrict__ attW,
                                                        const float* __restrict__ attb,
                                                        const float* __restrict__ tfidf,
                                                        float* __restrict__ e) {
    int seg = (blockIdx.x * 256 + threadIdx.x) >> 6;
    int lane = threadIdx.x & 63;
    if (seg >= nseg) return;
    int start = rowptr[seg], end = rowptr[seg + 1];
    float4 acc = make_float4(0.f, 0.f, 0.f, 0.f);
    for (int k = start; k < end; ++k) {
        int r; float v;
        if constexpr (MODE == 0) {
            int2 q = ((const int2*)listv)[k];
            r = q.x; v = __int_as_float(q.y);
        } else {
            int4 q = ((const int4*)listv)[k];
            r = (MODE == 1) ? q.x : q.y;
            v = __int_as_float(q.z);
        }
        ushort4 sv = *reinterpret_cast<const ushort4*>(src + (size_t)r * 256 + lane * 4);
        acc.x += v * bf2f(sv.x); acc.y += v * bf2f(sv.y);
        acc.z += v * bf2f(sv.z); acc.w += v * bf2f(sv.w);
    }
    float4 o = acc;
    if constexpr (EPI) {
        float4 bv = reinterpret_cast<const float4*>(bias)[lane];
        o.x = fmaxf(o.x + bv.x, 0.f); o.y = fmaxf(o.y + bv.y, 0.f);
        o.z = fmaxf(o.z + bv.z, 0.f); o.w = fmaxf(o.w + bv.w, 0.f);
    }
    ushort4 o4;
    o4.x = f2bf(o.x); o4.y = f2bf(o.y); o4.z = f2bf(o.z); o4.w = f2bf(o.w);
    *reinterpret_cast<ushort4*>(dst + (size_t)seg * 256 + lane * 4) = o4;
    if constexpr (ATT) {
        float4 aw = reinterpret_cast<const float4*>(attW)[lane];
        float pe = o.x * aw.x + o.y * aw.y + o.z * aw.z + o.w * aw.w;
#pragma unroll
        for (int off = 32; off > 0; off >>= 1) pe += __shfl_down(pe, off);
        if (lane == 0)
            e[seg] = pe + tfidf[seg * 2] * attW[HID_] + tfidf[seg * 2 + 1] * attW[HID_ + 1]
                     + attb[0];
    }
}

// ---------------- W -> transposed hi/lo bf16 split (both weights, fused) ------------
__global__ __launch_bounds__(256) void wconv_kernel(const float* __restrict__ W1,
                                                    const float* __restrict__ W2,
                                                    u16* __restrict__ Wt1h, u16* __restrict__ Wt1l,
                                                    u16* __restrict__ Wt2h, u16* __restrict__ Wt2l) {
    int idx = blockIdx.x * 256 + threadIdx.x;
    const float* W; u16 *Wh, *Wl; int K, KP;
    if (idx < 256 * 320) { W = W1; Wh = Wt1h; Wl = Wt1l; K = D_; KP = 320; }
    else { idx -= 256 * 320; if (idx >= 256 * 256) return;
           W = W2; Wh = Wt2h; Wl = Wt2l; K = HID_; KP = 256; }
    int n = idx & 255;
    int k = idx >> 8;
    float v = (k < K) ? W[(size_t)k * HID_ + n] : 0.f;
    u16 hi = f2bf(v);
    u16 lo = f2bf(v - bf2f(hi));
    Wh[(size_t)n * KP + k] = hi;
    Wl[(size_t)n * KP + k] = lo;
}

// ---------------- MFMA GEMM, full-N tile 64x256: C = A @ Wt^T -----------------------
template <bool SPLIT_A, bool EPI, bool ATT>
__global__ __launch_bounds__(256) void gemm_mfma_kernel(const void* __restrict__ Av,
                                                        int M, int K, int Ks,
                                                        const u16* __restrict__ Bth,
                                                        const u16* __restrict__ Btl, int bstride,
                                                        const float* __restrict__ bias,
                                                        void* __restrict__ Cv,
                                                        const float* __restrict__ attWA,
                                                        float* __restrict__ EAp,
                                                        const float* __restrict__ attW,
                                                        const float* __restrict__ attb,
                                                        const float* __restrict__ tfidf,
                                                        float* __restrict__ e) {
    __shared__ __align__(16) u16 Ah[64 * 32];
    __shared__ __align__(16) u16 Al[64 * 32];
    __shared__ __align__(16) u16 Bh[256 * 32];
    __shared__ __align__(16) u16 Bl[256 * 32];
    int tid = threadIdx.x;
    int bm0 = blockIdx.x * 64;
    int w = tid >> 6, l = tid & 63;
    int srow = tid >> 2;
    int skbp = tid & 3;
    int skbl = skbp ^ ((srow >> 1) & 3);
    int arow = bm0 + srow; if (arow >= M) arow = M - 1;
    int sdst = srow * 32 + skbp * 8;
    int frow = w * 16 + (l & 15);
    int akbp = (l >> 4) ^ ((frow >> 1) & 3);

    f32x4 acc[16] = {};
    float ea = 0.f;
    int nkt = (K + 31) / 32;
    for (int kt = 0; kt < nkt; ++kt) {
        if (kt) __syncthreads();
        int kbase = kt * 32 + skbl * 8;
        if constexpr (SPLIT_A) {
            const float* Arow = (const float*)Av + (size_t)arow * Ks;
            float av[8];
            if (kbase + 8 <= K) {
                float4 v0 = *reinterpret_cast<const float4*>(Arow + kbase);
                float4 v1 = *reinterpret_cast<const float4*>(Arow + kbase + 4);
                av[0] = v0.x; av[1] = v0.y; av[2] = v0.z; av[3] = v0.w;
                av[4] = v1.x; av[5] = v1.y; av[6] = v1.z; av[7] = v1.w;
            } else {
#pragma unroll
                for (int ee = 0; ee < 8; ++ee) {
                    int kk = kbase + ee;
                    av[ee] = (kk < K) ? Arow[kk] : 0.f;
                }
            }
            if (EAp) {
#pragma unroll
                for (int ee = 0; ee < 8; ++ee) {
                    int kk = kbase + ee;
                    ea += av[ee] * ((kk < K) ? attWA[kk] : 0.f);
                }
            }
            short8 h8, l8;
#pragma unroll
            for (int ee = 0; ee < 8; ++ee) {
                u16 hi = f2bf(av[ee]);
                h8[ee] = (short)hi;
                l8[ee] = (short)f2bf(av[ee] - bf2f(hi));
            }
            *(short8*)&Ah[sdst] = h8;
            *(short8*)&Al[sdst] = l8;
        } else {
            const u16* Arow = (const u16*)Av + (size_t)arow * Ks;
            *(short8*)&Ah[sdst] = *(const short8*)(Arow + kbase);
        }
#pragma unroll
        for (int i = 0; i < 4; ++i) {
            int br = i * 64 + srow;
            int bkl = skbp ^ ((br >> 1) & 3);
            *(short8*)&Bh[br * 32 + skbp * 8] =
                *(const short8*)(Bth + (size_t)br * bstride + kt * 32 + bkl * 8);
            *(short8*)&Bl[br * 32 + skbp * 8] =
                *(const short8*)(Btl + (size_t)br * bstride + kt * 32 + bkl * 8);
        }
        __syncthreads();
        short8 ah = *(const short8*)&Ah[frow * 32 + akbp * 8];
        short8 al;
        if constexpr (SPLIT_A) al = *(const short8*)&Al[frow * 32 + akbp * 8];
#pragma unroll
        for (int nt = 0; nt < 16; ++nt) {
            int nrow = nt * 16 + (l & 15);
            int bkbp = (l >> 4) ^ ((nrow >> 1) & 3);
            short8 tbh = *(const short8*)&Bh[nrow * 32 + bkbp * 8];
            short8 tbl = *(const short8*)&Bl[nrow * 32 + bkbp * 8];
            acc[nt] = __builtin_amdgcn_mfma_f32_16x16x32_bf16(ah, tbh, acc[nt], 0, 0, 0);
            if constexpr (SPLIT_A)
                acc[nt] = __builtin_amdgcn_mfma_f32_16x16x32_bf16(al, tbh, acc[nt], 0, 0, 0);
            acc[nt] = __builtin_amdgcn_mfma_f32_16x16x32_bf16(ah, tbl, acc[nt], 0, 0, 0);
        }
    }
    if constexpr (SPLIT_A) {
        if (EAp) {
            ea += __shfl_xor(ea, 1);
            ea += __shfl_xor(ea, 2);
            if ((tid & 3) == 0 && bm0 + srow < M) EAp[bm0 + srow] = ea;
        }
    }
#pragma unroll
    for (int r = 0; r < 4; ++r) {
        int row = bm0 + w * 16 + (l >> 4) * 4 + r;
        if (row >= M) continue;
        float er = 0.f;
#pragma unroll
        for (int nt = 0; nt < 16; ++nt) {
            int col = nt * 16 + (l & 15);
            float v = acc[nt][r];
            if constexpr (EPI) {
                v = v + bias[col];
                v = v > 0.f ? v : 0.f;
            }
            if constexpr (ATT) er += v * attW[col];
            ((u16*)Cv)[(size_t)row * 256 + col] = f2bf(v);
        }
        if constexpr (ATT) {
            er += __shfl_xor(er, 1);
            er += __shfl_xor(er, 2);
            er += __shfl_xor(er, 4);
            er += __shfl_xor(er, 8);
            if ((l & 15) == 0)
                e[row] = er + tfidf[row * 2] * attW[HID_] + tfidf[row * 2 + 1] * attW[HID_ + 1]
                         + attb[0];
        }
    }
}

// ---------------- pool partial: fused per-graph softmax + weighted-sum + max --------
// grid (B, PCHUNK); block 256. Each block computes the graph softmax from all 512
// logits (cheap, shared), then pools its 64-node chunk.
// L0: h = f32 emb rows via x[], logits from EA[x]+tfidf; else h bf16, logits e[].
template <bool L0>
__global__ __launch_bounds__(256) void pool_partial_kernel(const void* __restrict__ h, int dim,
                                                           int stride,
                                                           const int* __restrict__ x,
                                                           const float* __restrict__ EA_or_e,
                                                           const float* __restrict__ tfidf,
                                                           const float* __restrict__ attWtail,
                                                           const float* __restrict__ attb,
                                                           float* __restrict__ psum,
                                                           float* __restrict__ pmax) {
    int b = blockIdx.x, c = blockIdx.y;
    int t = threadIdx.x;
    __shared__ float sev[N_];
    __shared__ int srows[N_];
    __shared__ float red[256];
    __shared__ float wv[PVN];
    int n0 = b * N_ + t, n1 = n0 + 256;
    float ev0, ev1;
    int r0, r1;
    if constexpr (L0) {
        r0 = x[n0]; r1 = x[n1];
        float a0 = attWtail[0], a1 = attWtail[1], ab = attb[0];
        ev0 = EA_or_e[r0] + tfidf[n0 * 2] * a0 + tfidf[n0 * 2 + 1] * a1 + ab;
        ev1 = EA_or_e[r1] + tfidf[n1 * 2] * a0 + tfidf[n1 * 2 + 1] * a1 + ab;
    } else {
        r0 = n0; r1 = n1;
        ev0 = EA_or_e[n0]; ev1 = EA_or_e[n1];
    }
    sev[t] = ev0; sev[t + 256] = ev1;
    srows[t] = r0; srows[t + 256] = r1;
    red[t] = fmaxf(ev0, ev1);
    __syncthreads();
    for (int s = 128; s > 0; s >>= 1) {
        if (t < s) red[t] = fmaxf(red[t], red[t + s]);
        __syncthreads();
    }
    float mx = red[0];
    __syncthreads();
    red[t] = expf(ev0 - mx) + expf(ev1 - mx);
    __syncthreads();
    for (int s = 128; s > 0; s >>= 1) {
        if (t < s) red[t] += red[t + s];
        __syncthreads();
    }
    float inv = 1.f / (red[0] + 1e-10f);
    if (t < PVN) wv[t] = expf(sev[c * PVN + t] - mx) * inv;
    __syncthreads();
    float s0 = 0.f, s1 = 0.f, m0 = -3.4e38f, m1 = -3.4e38f;
    int d0 = t, d1 = t + 256;
    bool has1 = d1 < dim;
    for (int i = 0; i < PVN; ++i) {
        int row = srows[c * PVN + i];
        float ww = wv[i];
        float x0, x1 = 0.f;
        if constexpr (L0) {
            const float* hp = (const float*)h + (size_t)row * stride;
            x0 = hp[d0];
            if (has1) x1 = hp[d1];
        } else {
            const u16* hp = (const u16*)h + (size_t)row * stride;
            x0 = bf2f(hp[d0]);
            if (has1) x1 = bf2f(hp[d1]);
        }
        s0 += ww * x0;
        m0 = fmaxf(m0, x0);
        if (has1) {
            s1 += ww * x1;
            m1 = fmaxf(m1, x1);
        }
    }
    size_t base = ((size_t)b * PCHUNK + c) * dim;
    psum[base + d0] = s0;
    pmax[base + d0] = m0;
    if (has1) {
        psum[base + d1] = s1;
        pmax[base + d1] = m1;
    }
}

// ---------------- pool stage C: combine chunk partials -------------------------------
__global__ __launch_bounds__(256) void pool_combine_kernel(const float* __restrict__ psum,
                                                           const float* __restrict__ pmax,
                                                           int dim, float* __restrict__ p) {
    int b = blockIdx.x;
    for (int d = threadIdx.x; d < dim; d += 256) {
        float s = 0.f, m = -3.4e38f;
        for (int c = 0; c < PCHUNK; ++c) {
            size_t base = ((size_t)b * PCHUNK + c) * dim;
            s += psum[base + d];
            m = fmaxf(m, pmax[base + d]);
        }
        p[(size_t)b * 2 * dim + d] = s;
        p[(size_t)b * 2 * dim + dim + d] = m;
    }
}

// ---------------- final prediction (parallel GEMV, 256 thr/graph) --------------------
__global__ __launch_bounds__(256) void final_kernel(const float* __restrict__ p0,
                                                    const float* __restrict__ p1,
                                                    const float* __restrict__ p2,
                                                    const float* __restrict__ pW0,
                                                    const float* __restrict__ pb0,
                                                    const float* __restrict__ pW1,
                                                    const float* __restrict__ pb1,
                                                    const float* __restrict__ pW2,
                                                    const float* __restrict__ pb2,
                                                    float* __restrict__ out) {
    int b = blockIdx.x;
    int t = threadIdx.x;
    int lane = t & 63, wv = t >> 6;
    float acc[NC_] = {};
    for (int k = t; k < 2 * D_; k += 256) {
        float pv = p0[(size_t)b * 2 * D_ + k];
        const float* wp = pW0 + (size_t)k * NC_;
#pragma unroll
        for (int c = 0; c < NC_; ++c) acc[c] += pv * wp[c];
    }
    for (int k = t; k < 2 * HID_; k += 256) {
        float pv = p1[(size_t)b * 2 * HID_ + k];
        const float* wp = pW1 + (size_t)k * NC_;
#pragma unroll
        for (int c = 0; c < NC_; ++c) acc[c] += pv * wp[c];
    }
    for (int k = t; k < 2 * HID_; k += 256) {
        float pv = p2[(size_t)b * 2 * HID_ + k];
        const float* wp = pW2 + (size_t)k * NC_;
#pragma unroll
        for (int c = 0; c < NC_; ++c) acc[c] += pv * wp[c];
    }
    __shared__ float red[4][NC_];
#pragma unroll
    for (int c = 0; c < NC_; ++c) {
        float s = acc[c];
#pragma unroll
        for (int off = 32; off > 0; off >>= 1) s += __shfl_down(s, off);
        if (lane == 0) red[wv][c] = s;
    }
    __syncthreads();
    if (t < NC_) {
        float s = red[0][t] + red[1][t] + red[2][t] + red[3][t];
        out[b * NC_ + t] = s + pb0[t] + pb1[t] + pb2[t];
    }
}

extern "C" void kernel_launch(void* const* d_in, const int* in_sizes, int n_in,
                              void* d_out, int out_size, void* d_ws, size_t ws_size,
                              hipStream_t stream) {
    const int*   x         = (const int*)d_in[0];
    const int*   inc_rows  = (const int*)d_in[1];
    const int*   inc_cols  = (const int*)d_in[2];
    const float* inc_vals  = (const float*)d_in[3];
    const int*   sent_rows = (const int*)d_in[4];
    const int*   sent_cols = (const int*)d_in[5];
    const float* sent_vals = (const float*)d_in[6];
    const float* deg_v     = (const float*)d_in[7];
    const float* deg_e     = (const float*)d_in[8];
    const float* tf_idf = (const float*)d_in[11];
    const float* emb    = (const float*)d_in[12];
    const float* W1 = (const float*)d_in[13];
    const float* b1 = (const float*)d_in[14];
    const float* W2 = (const float*)d_in[15];
    const float* b2 = (const float*)d_in[16];
    const float* attW0 = (const float*)d_in[17];
    const float* attb0 = (const float*)d_in[18];
    const float* attW1 = (const float*)d_in[19];
    const float* attb1 = (const float*)d_in[20];
    const float* attW2 = (const float*)d_in[21];
    const float* attb2 = (const float*)d_in[22];
    const float* pW0 = (const float*)d_in[23];
    const float* pb0 = (const float*)d_in[24];
    const float* pW1 = (const float*)d_in[25];
    const float* pb1 = (const float*)d_in[26];
    const float* pW2 = (const float*)d_in[27];
    const float* pb2 = (const float*)d_in[28];
    float* out = (float*)d_out;

    // workspace layout
    char* ws = (char*)d_ws;
    size_t off = 0;
    auto alloc = [&](size_t bytes) {
        void* p = ws + off;
        off += (bytes + 255) & ~(size_t)255;
        return p;
    };
    u16* EW = (u16*)alloc((size_t)VOCAB_ * HID_ * sizeof(u16)); // emb @ W1, bf16
    u16* hv = (u16*)alloc((size_t)NV_ * HID_ * sizeof(u16));
    u16* m  = (u16*)alloc((size_t)NE_ * HID_ * sizeof(u16));
    u16* m2 = (u16*)alloc((size_t)NE_ * HID_ * sizeof(u16));
    u16* h1 = (u16*)alloc((size_t)NV_ * HID_ * sizeof(u16));
    u16* h2 = (u16*)alloc((size_t)NV_ * HID_ * sizeof(u16));
    u16* Wt1h = (u16*)alloc((size_t)HID_ * 320 * sizeof(u16));
    u16* Wt1l = (u16*)alloc((size_t)HID_ * 320 * sizeof(u16));
    u16* Wt2h = (u16*)alloc((size_t)HID_ * 256 * sizeof(u16));
    u16* Wt2l = (u16*)alloc((size_t)HID_ * 256 * sizeof(u16));
    float* EA = (float*)alloc((size_t)VOCAB_ * sizeof(float));  // emb @ attW0[:300]
    float* e  = (float*)alloc((size_t)NV_ * sizeof(float));
    float* psum = (float*)alloc((size_t)B_ * PCHUNK * D_ * sizeof(float));
    float* pmax = (float*)alloc((size_t)B_ * PCHUNK * D_ * sizeof(float));
    float* p0 = (float*)alloc((size_t)B_ * 2 * D_ * sizeof(float));
    float* p1 = (float*)alloc((size_t)B_ * 2 * HID_ * sizeof(float));
    float* p2 = (float*)alloc((size_t)B_ * 2 * HID_ * sizeof(float));
    // CSR structures
    int* cnt  = (int*)alloc((size_t)SCAN_TOT * sizeof(int));  // [cnt_e|cnt_v|cnt_s]
    int* fill = (int*)alloc((size_t)SCAN_TOT * sizeof(int));
    int* rowptr_e = (int*)alloc((size_t)(NE_ + 1) * sizeof(int));
    int* rowptr_v = (int*)alloc((size_t)(NV_ + 1) * sizeof(int));
    int* rowptr_s = (int*)alloc((size_t)(NE_ + 1) * sizeof(int));
    int* bsum  = (int*)alloc((size_t)SCAN_NCH * sizeof(int));
    int* cbase = (int*)alloc((size_t)SCAN_NCH * sizeof(int));
    int4* elist = (int4*)alloc((size_t)NNZ_ * sizeof(int4));
    int2* vlist = (int2*)alloc((size_t)NNZ_ * sizeof(int2));
    int2* slist = (int2*)alloc((size_t)SNNZ_ * sizeof(int2));

    // ---- build CSR (fused hist / scan / packed place with deg folding) ----
    hipMemsetAsync(cnt, 0, (size_t)SCAN_TOT * sizeof(int), stream);
    hist_kernel<<<NNZ_ / 256, 256, 0, stream>>>(inc_rows, inc_cols, sent_cols, cnt);
    scanA_kernel<<<SCAN_NCH, 256, 0, stream>>>(cnt, bsum);
    scanB_kernel<<<1, 64, 0, stream>>>(bsum, cbase);
    scanC_kernel<<<SCAN_NCH, 256, 0, stream>>>(cnt, cbase, rowptr_e, rowptr_v, rowptr_s, fill);
    place_kernel<<<NNZ_ / 256, 256, 0, stream>>>(inc_rows, inc_cols, inc_vals,
                                                 sent_rows, sent_cols, sent_vals,
                                                 x, deg_e, deg_v, fill,
                                                 elist, vlist, slist);

    // ---- weight conversion (both layers, one launch) ----
    wconv_kernel<<<(256 * 320 + 256 * 256 + 255) / 256, 256, 0, stream>>>(
        W1, W2, Wt1h, Wt1l, Wt2h, Wt2l);

    // ---- EW = emb @ W1 (bf16 out) + EA = emb @ attW0 (free, f32) ----
    gemm_mfma_kernel<true, false, false><<<(VOCAB_ + 63) / 64, 256, 0, stream>>>(
        emb, VOCAB_, D_, D_, Wt1h, Wt1l, 320, nullptr, EW,
        attW0, EA, nullptr, nullptr, nullptr, nullptr);

    // ---- pool layer 0 (fused softmax+partial; logits from EA) ----
    {
        dim3 pg(B_, PCHUNK);
        pool_partial_kernel<true><<<pg, 256, 0, stream>>>(emb, D_, D_, x, EA,
                                                          tf_idf, attW0 + D_, attb0,
                                                          psum, pmax);
        pool_combine_kernel<<<B_, 256, 0, stream>>>(psum, pmax, D_, p0);
    }

    // ---- layer 1 sparse chain @ dim 256 (deg folded into vals) ----
    gather256_kernel<2, false, false><<<NE_ / 4, 256, 0, stream>>>(
        rowptr_e, elist, EW, nullptr, m, NE_, nullptr, nullptr, nullptr, nullptr);
    gather256_kernel<0, false, false><<<NE_ / 4, 256, 0, stream>>>(
        rowptr_s, slist, m, nullptr, m2, NE_, nullptr, nullptr, nullptr, nullptr);
    gather256_kernel<0, true, true><<<NV_ / 4, 256, 0, stream>>>(
        rowptr_v, vlist, m2, b1, h1, NV_, attW1, attb1, tf_idf, e);

    // ---- pool layer 1 ----
    {
        dim3 pg(B_, PCHUNK);
        pool_partial_kernel<false><<<pg, 256, 0, stream>>>(h1, HID_, HID_, nullptr, e,
                                                           nullptr, nullptr, nullptr,
                                                           psum, pmax);
        pool_combine_kernel<<<B_, 256, 0, stream>>>(psum, pmax, HID_, p1);
    }

    // ---- layer 2 ----
    gather256_kernel<1, false, false><<<NE_ / 4, 256, 0, stream>>>(
        rowptr_e, elist, h1, nullptr, m, NE_, nullptr, nullptr, nullptr, nullptr);
    gather256_kernel<0, false, false><<<NE_ / 4, 256, 0, stream>>>(
        rowptr_s, slist, m, nullptr, m2, NE_, nullptr, nullptr, nullptr, nullptr);
    gather256_kernel<0, false, false><<<NV_ / 4, 256, 0, stream>>>(
        rowptr_v, vlist, m2, nullptr, hv, NV_, nullptr, nullptr, nullptr, nullptr);
    // h2 = relu(hv @ W2 + b2) (deg_v already in hv) + e2 in epilogue
    gemm_mfma_kernel<false, true, true><<<NV_ / 64, 256, 0, stream>>>(
        hv, NV_, HID_, HID_, Wt2h, Wt2l, 256, b2, h2,
        nullptr, nullptr, attW2, attb2, tf_idf, e);

    // ---- pool layer 2 ----
    {
        dim3 pg(B_, PCHUNK);
        pool_partial_kernel<false><<<pg, 256, 0, stream>>>(h2, HID_, HID_, nullptr, e,
                                                           nullptr, nullptr, nullptr,
                                                           psum, pmax);
        pool_combine_kernel<<<B_, 256, 0, stream>>>(psum, pmax, HID_, p2);
    }

    // ---- final linear ----
    final_kernel<<<B_, 256, 0, stream>>>(p0, p1, p2, pW0, pb0, pW1, pb1, pW2, pb2, out);
}